// Round 4
// baseline (293.993 us; speedup 1.0000x reference)
//
#include <hip/hip_runtime.h>

#define B_ 4
#define S_ 2048
#define D_ 512
#define H_ 8
#define DP_ 64
#define NT_ (S_/64)

typedef __attribute__((ext_vector_type(4))) float f32x4;
typedef __attribute__((ext_vector_type(8))) short short8;

__device__ __forceinline__ short f2bf(float f){
  unsigned u = __float_as_uint(f);
  u += 0x7fff + ((u >> 16) & 1);   // round-to-nearest-even
  return (short)(u >> 16);
}

// element-offset swizzle for 64-element (128B) rows: XOR 8-elem granule with row&7
#define SWZ(r, kb) ((r)*64 + ((kb) ^ (((r)&7)<<3)))

// stage 64-elem-wide rows into linear LDS via global_load_lds, inverse-swizzled source
// (rule #21). NC KB per wave; NW = waves in block. Tile bytes = NC*NW KB.
template<int NC, int NW>
__device__ __forceinline__ void stage_tile(const short* __restrict__ g, int rowStride,
                                           short* shbase, int w, int l){
  #pragma unroll
  for(int i = 0; i < NC; ++i){
    int byte = (w*NC + i)*1024 + l*16;
    int row = byte >> 7;
    int gs = ((byte >> 4) & 7) ^ (row & 7);
    const short* src = g + (size_t)row*rowStride + gs*8;
    __builtin_amdgcn_global_load_lds((const __attribute__((address_space(1))) void*)src,
        (__attribute__((address_space(3))) void*)(shbase + (w*NC + i)*512), 16, 0, 0);
  }
}

// ---------------- 4 weight transposes + cast to bf16 (z-sliced) ----------------
__global__ void k_prep(const float* __restrict__ w0, const float* __restrict__ w1,
                       const float* __restrict__ w2, const float* __restrict__ w3,
                       short* __restrict__ t0, short* __restrict__ t1,
                       short* __restrict__ t2, short* __restrict__ t3){
  __shared__ float t[32][33];
  const float* w = blockIdx.z == 0 ? w0 : blockIdx.z == 1 ? w1 : blockIdx.z == 2 ? w2 : w3;
  short* wt = blockIdx.z == 0 ? t0 : blockIdx.z == 1 ? t1 : blockIdx.z == 2 ? t2 : t3;
  int bx = blockIdx.x * 32, by = blockIdx.y * 32;
  int tx = threadIdx.x, ty = threadIdx.y;   // block (32,8)
  #pragma unroll
  for(int i = 0; i < 32; i += 8) t[ty + i][tx] = w[(by + ty + i) * D_ + bx + tx];
  __syncthreads();
  #pragma unroll
  for(int i = 0; i < 32; i += 8) wt[(bx + ty + i) * D_ + by + tx] = f2bf(t[tx][ty + i]);
}

// ---------------- cast q,k,v f32 -> bf16 (z-sliced) ----------------
__global__ void k_cast(const float* __restrict__ q, const float* __restrict__ k,
                       const float* __restrict__ v, short* __restrict__ dst){
  const float* s = blockIdx.z == 0 ? q : blockIdx.z == 1 ? k : v;
  short* d = dst + (size_t)blockIdx.z * (B_ * S_ * D_);
  int i = blockIdx.x * 256 + threadIdx.x;
  float4 a = ((const float4*)s)[i * 2];
  float4 b = ((const float4*)s)[i * 2 + 1];
  short8 o;
  o[0]=f2bf(a.x); o[1]=f2bf(a.y); o[2]=f2bf(a.z); o[3]=f2bf(a.w);
  o[4]=f2bf(b.x); o[5]=f2bf(b.y); o[6]=f2bf(b.z); o[7]=f2bf(b.w);
  ((short8*)d)[i] = o;
}

// ---------------- mask -> float bias ----------------
__global__ void k_maskbias(const int* __restrict__ mask, float* __restrict__ mb){
  int i = blockIdx.x * 256 + threadIdx.x;
  if(i < B_ * S_) mb[i] = mask[i] ? -1.0e9f : 0.0f;
}

// ---------------- fused QKV GEMM: 128x128 tile, 4 waves ----------------
// z=0: q@wqT -> qh [B][H][S][64]; z=1: k@wkT -> kh; z=2: v@wvT -> vvt [B][H][64][S]
__global__ __launch_bounds__(256) void k_gemm_qkv(const short* __restrict__ Xall,
        const short* __restrict__ WTall, const float* __restrict__ b0,
        const float* __restrict__ b1, const float* __restrict__ b2,
        short* __restrict__ qh, short* __restrict__ kh, short* __restrict__ vvt){
  __shared__ __align__(16) short As[2][8192];
  __shared__ __align__(16) short Bs[2][8192];
  const int z = blockIdx.z;
  const short* X  = Xall + (size_t)z * (B_*S_*D_);
  const short* WT = WTall + (size_t)z * (D_*D_);
  const float* bias = z==0 ? b0 : (z==1 ? b1 : b2);
  const int t = threadIdx.x, l = t & 63, w = t >> 6;
  const int lr = l & 15, lg = l >> 4;
  const int m0 = blockIdx.x * 128, n0 = blockIdx.y * 128;
  const int wr = w >> 1, wc = w & 1;
  const short* Xb = X + (size_t)m0 * D_;
  const short* Wb = WT + (size_t)n0 * D_;
  f32x4 acc[4][4] = {};
  stage_tile<4,4>(Xb, D_, As[0], w, l);
  stage_tile<4,4>(Wb, D_, Bs[0], w, l);
  __syncthreads();
  for(int kt = 0; kt < D_ / 64; ++kt){
    if(kt + 1 < D_ / 64){
      stage_tile<4,4>(Xb + (kt+1)*64, D_, As[(kt+1)&1], w, l);
      stage_tile<4,4>(Wb + (kt+1)*64, D_, Bs[(kt+1)&1], w, l);
    }
    const short* Ac = As[kt&1];
    const short* Bc = Bs[kt&1];
    #pragma unroll
    for(int ks = 0; ks < 2; ++ks){
      const int kb = ks*32 + lg*8;
      short8 a[4], b[4];
      #pragma unroll
      for(int mt = 0; mt < 4; ++mt)
        a[mt] = *reinterpret_cast<const short8*>(&Ac[SWZ(wr*64 + mt*16 + lr, kb)]);
      #pragma unroll
      for(int nt = 0; nt < 4; ++nt)
        b[nt] = *reinterpret_cast<const short8*>(&Bc[SWZ(wc*64 + nt*16 + lr, kb)]);
      __builtin_amdgcn_s_setprio(1);
      #pragma unroll
      for(int mt = 0; mt < 4; ++mt)
        #pragma unroll
        for(int nt = 0; nt < 4; ++nt)
          acc[mt][nt] = __builtin_amdgcn_mfma_f32_16x16x32_bf16(a[mt], b[nt], acc[mt][nt], 0, 0, 0);
      __builtin_amdgcn_s_setprio(0);
    }
    __syncthreads();
  }
  #pragma unroll
  for(int mt = 0; mt < 4; ++mt){
    #pragma unroll
    for(int nt = 0; nt < 4; ++nt){
      const int n = n0 + wc*64 + nt*16 + lr;
      const int m4 = m0 + wr*64 + mt*16 + lg*4;
      float vals[4];
      #pragma unroll
      for(int r = 0; r < 4; ++r) vals[r] = acc[mt][nt][r] + bias[n];
      if(z == 2){
        short4 pv4;
        pv4.x = f2bf(vals[0]); pv4.y = f2bf(vals[1]); pv4.z = f2bf(vals[2]); pv4.w = f2bf(vals[3]);
        *reinterpret_cast<short4*>(&vvt[
            (((size_t)((m4 >> 11) * H_ + (n >> 6))) * DP_ + (n & 63)) * S_ + (m4 & 2047)]) = pv4;
      } else {
        short* dst = z == 0 ? qh : kh;
        #pragma unroll
        for(int r = 0; r < 4; ++r){
          int m = m4 + r;
          dst[(((size_t)((m >> 11) * H_ + (n >> 6))) * S_ + (m & 2047)) * DP_ + (n & 63)] = f2bf(vals[r]);
        }
      }
    }
  }
}

// ---------------- out GEMM: ctx[8192,512]bf16 @ woT + bo -> f32 ----------------
__global__ __launch_bounds__(256) void k_gemm_out(const short* __restrict__ X,
        const short* __restrict__ WT, const float* __restrict__ bias,
        float* __restrict__ Out){
  __shared__ __align__(16) short As[2][8192];
  __shared__ __align__(16) short Bs[2][8192];
  const int t = threadIdx.x, l = t & 63, w = t >> 6;
  const int lr = l & 15, lg = l >> 4;
  const int m0 = blockIdx.x * 128, n0 = blockIdx.y * 128;
  const int wr = w >> 1, wc = w & 1;
  const short* Xb = X + (size_t)m0 * D_;
  const short* Wb = WT + (size_t)n0 * D_;
  f32x4 acc[4][4] = {};
  stage_tile<4,4>(Xb, D_, As[0], w, l);
  stage_tile<4,4>(Wb, D_, Bs[0], w, l);
  __syncthreads();
  for(int kt = 0; kt < D_ / 64; ++kt){
    if(kt + 1 < D_ / 64){
      stage_tile<4,4>(Xb + (kt+1)*64, D_, As[(kt+1)&1], w, l);
      stage_tile<4,4>(Wb + (kt+1)*64, D_, Bs[(kt+1)&1], w, l);
    }
    const short* Ac = As[kt&1];
    const short* Bc = Bs[kt&1];
    #pragma unroll
    for(int ks = 0; ks < 2; ++ks){
      const int kb = ks*32 + lg*8;
      short8 a[4], b[4];
      #pragma unroll
      for(int mt = 0; mt < 4; ++mt)
        a[mt] = *reinterpret_cast<const short8*>(&Ac[SWZ(wr*64 + mt*16 + lr, kb)]);
      #pragma unroll
      for(int nt = 0; nt < 4; ++nt)
        b[nt] = *reinterpret_cast<const short8*>(&Bc[SWZ(wc*64 + nt*16 + lr, kb)]);
      __builtin_amdgcn_s_setprio(1);
      #pragma unroll
      for(int mt = 0; mt < 4; ++mt)
        #pragma unroll
        for(int nt = 0; nt < 4; ++nt)
          acc[mt][nt] = __builtin_amdgcn_mfma_f32_16x16x32_bf16(a[mt], b[nt], acc[mt][nt], 0, 0, 0);
      __builtin_amdgcn_s_setprio(0);
    }
    __syncthreads();
  }
  #pragma unroll
  for(int mt = 0; mt < 4; ++mt){
    #pragma unroll
    for(int nt = 0; nt < 4; ++nt){
      const int n = n0 + wc*64 + nt*16 + lr;
      const int m4 = m0 + wr*64 + mt*16 + lg*4;
      #pragma unroll
      for(int r = 0; r < 4; ++r)
        Out[(size_t)(m4 + r) * D_ + n] = acc[mt][nt][r] + bias[n];
    }
  }
}

// ---------------- fused attention ----------------
// 4 waves, q-tile 128 (32 q-rows/wave, 2 qsub). Swapped QK^T: lane -> (q=lr, k=lg*4+r).
// LDS (shorts): K dbuf [0,8192), VT dbuf [8192,16384), Q-then-P [16384,24576)  (48 KB)
__global__ __launch_bounds__(256, 3) void k_attn(const short* __restrict__ qh,
                                                 const short* __restrict__ kh,
                                                 const short* __restrict__ vt,
                                                 const float* __restrict__ mb,
                                                 float* __restrict__ attn,
                                                 short* __restrict__ ctx){
  __shared__ __align__(16) short Sh[24576];
  const int t = threadIdx.x, l = t & 63, w = t >> 6;
  const int lr = l & 15, lg = l >> 4;
  const int bh = blockIdx.y, b = bh >> 3, h = bh & 7;
  const int q0 = blockIdx.x * 128;
  const short* Qb = qh + (size_t)bh * S_ * DP_ + (size_t)q0 * DP_;
  const short* Kb = kh + (size_t)bh * S_ * DP_;
  const short* Vtb = vt + (size_t)bh * DP_ * S_;
  const float* Mbb = mb + b * S_;
  const float scale = 0.125f;

  // stage Q (128x64, 16KB) into the Q/P region, K tile 0 into buf0
  stage_tile<4,4>(Qb, DP_, Sh + 16384, w, l);
  stage_tile<2,4>(Kb, DP_, Sh, w, l);
  __syncthreads();
  short8 bq[2][2];
  #pragma unroll
  for(int qsub = 0; qsub < 2; ++qsub){
    int r = w * 32 + qsub * 16 + lr;
    #pragma unroll
    for(int ks = 0; ks < 2; ++ks)
      bq[qsub][ks] = *reinterpret_cast<const short8*>(&Sh[16384 + SWZ(r, ks * 32 + lg * 8)]);
  }

  // ---------------- pass A: row sums ----------------
  float ps[2] = {0.f, 0.f};
  for(int kt = 0; kt < NT_; ++kt){
    const short* Kc = Sh + (kt & 1) * 4096;
    if(kt + 1 < NT_)
      stage_tile<2,4>(Kb + (size_t)(kt + 1) * 64 * DP_, DP_, Sh + ((kt + 1) & 1) * 4096, w, l);
    #pragma unroll
    for(int st = 0; st < 4; ++st){
      const float4 mv = *reinterpret_cast<const float4*>(&Mbb[kt * 64 + st * 16 + lg * 4]);
      short8 ak0 = *reinterpret_cast<const short8*>(&Kc[SWZ(st * 16 + lr, lg * 8)]);
      short8 ak1 = *reinterpret_cast<const short8*>(&Kc[SWZ(st * 16 + lr, 32 + lg * 8)]);
      #pragma unroll
      for(int qsub = 0; qsub < 2; ++qsub){
        __builtin_amdgcn_s_setprio(1);
        f32x4 c = {};
        c = __builtin_amdgcn_mfma_f32_16x16x32_bf16(ak0, bq[qsub][0], c, 0, 0, 0);
        c = __builtin_amdgcn_mfma_f32_16x16x32_bf16(ak1, bq[qsub][1], c, 0, 0, 0);
        __builtin_amdgcn_s_setprio(0);
        ps[qsub] += __expf(__builtin_fmaf(c[0], scale, mv.x));
        ps[qsub] += __expf(__builtin_fmaf(c[1], scale, mv.y));
        ps[qsub] += __expf(__builtin_fmaf(c[2], scale, mv.z));
        ps[qsub] += __expf(__builtin_fmaf(c[3], scale, mv.w));
      }
    }
    __syncthreads();
  }
  #pragma unroll
  for(int qsub = 0; qsub < 2; ++qsub){
    ps[qsub] += __shfl_xor(ps[qsub], 16, 64);
    ps[qsub] += __shfl_xor(ps[qsub], 32, 64);
  }
  const float rinv0 = 1.f / ps[0], rinv1 = 1.f / ps[1];

  // ---------------- pass B: normalized attn write + PV ----------------
  f32x4 o[2][4] = {};
  short* Pw = Sh + 16384 + w * 2048;               // 32x64 bf16 per wave
  stage_tile<2,4>(Kb, DP_, Sh, w, l);
  stage_tile<2,4>(Vtb, S_, Sh + 8192, w, l);
  __syncthreads();
  for(int kt = 0; kt < NT_; ++kt){
    const short* Kc = Sh + (kt & 1) * 4096;
    const short* Vc = Sh + 8192 + (kt & 1) * 4096;
    if(kt + 1 < NT_){
      stage_tile<2,4>(Kb + (size_t)(kt + 1) * 64 * DP_, DP_, Sh + ((kt + 1) & 1) * 4096, w, l);
      stage_tile<2,4>(Vtb + (size_t)(kt + 1) * 64, S_, Sh + 8192 + ((kt + 1) & 1) * 4096, w, l);
    }
    #pragma unroll
    for(int st = 0; st < 4; ++st){
      const float4 mv = *reinterpret_cast<const float4*>(&Mbb[kt * 64 + st * 16 + lg * 4]);
      short8 ak0 = *reinterpret_cast<const short8*>(&Kc[SWZ(st * 16 + lr, lg * 8)]);
      short8 ak1 = *reinterpret_cast<const short8*>(&Kc[SWZ(st * 16 + lr, 32 + lg * 8)]);
      #pragma unroll
      for(int qsub = 0; qsub < 2; ++qsub){
        const float rinv = qsub ? rinv1 : rinv0;
        __builtin_amdgcn_s_setprio(1);
        f32x4 c = {};
        c = __builtin_amdgcn_mfma_f32_16x16x32_bf16(ak0, bq[qsub][0], c, 0, 0, 0);
        c = __builtin_amdgcn_mfma_f32_16x16x32_bf16(ak1, bq[qsub][1], c, 0, 0, 0);
        __builtin_amdgcn_s_setprio(0);
        float4 pw;
        pw.x = __expf(__builtin_fmaf(c[0], scale, mv.x)) * rinv;
        pw.y = __expf(__builtin_fmaf(c[1], scale, mv.y)) * rinv;
        pw.z = __expf(__builtin_fmaf(c[2], scale, mv.z)) * rinv;
        pw.w = __expf(__builtin_fmaf(c[3], scale, mv.w)) * rinv;
        const int q = q0 + w * 32 + qsub * 16 + lr;
        *reinterpret_cast<float4*>(&attn[((size_t)bh * S_ + q) * S_ + kt * 64 + st * 16 + lg * 4]) = pw;
        short4 pb;
        pb.x = f2bf(pw.x); pb.y = f2bf(pw.y); pb.z = f2bf(pw.z); pb.w = f2bf(pw.w);
        *reinterpret_cast<short4*>(&Pw[SWZ(qsub * 16 + lr, st * 16 + lg * 4)]) = pb;
      }
    }
    #pragma unroll
    for(int ks = 0; ks < 2; ++ks){
      short8 pa0 = *reinterpret_cast<const short8*>(&Pw[SWZ(lr, ks * 32 + lg * 8)]);
      short8 pa1 = *reinterpret_cast<const short8*>(&Pw[SWZ(16 + lr, ks * 32 + lg * 8)]);
      __builtin_amdgcn_s_setprio(1);
      #pragma unroll
      for(int dt = 0; dt < 4; ++dt){
        short8 vb = *reinterpret_cast<const short8*>(&Vc[SWZ(dt * 16 + lr, ks * 32 + lg * 8)]);
        o[0][dt] = __builtin_amdgcn_mfma_f32_16x16x32_bf16(pa0, vb, o[0][dt], 0, 0, 0);
        o[1][dt] = __builtin_amdgcn_mfma_f32_16x16x32_bf16(pa1, vb, o[1][dt], 0, 0, 0);
      }
      __builtin_amdgcn_s_setprio(0);
    }
    __syncthreads();
  }
  // write context (head-merged bf16 [B][S][512]); o already normalized
  #pragma unroll
  for(int qsub = 0; qsub < 2; ++qsub){
    #pragma unroll
    for(int dt = 0; dt < 4; ++dt){
      #pragma unroll
      for(int r = 0; r < 4; ++r){
        int q = q0 + w * 32 + qsub * 16 + lg * 4 + r;
        int dd = h * 64 + dt * 16 + lr;
        ctx[((size_t)b * S_ + q) * D_ + dd] = f2bf(o[qsub][dt][r]);
      }
    }
  }
}

extern "C" void kernel_launch(void* const* d_in, const int* in_sizes, int n_in,
                              void* d_out, int out_size, void* d_ws, size_t ws_size,
                              hipStream_t stream){
  const float* q  = (const float*)d_in[0];
  const float* k  = (const float*)d_in[1];
  const float* v  = (const float*)d_in[2];
  const int* mask = (const int*)d_in[3];
  const float* wq = (const float*)d_in[4];
  const float* bq = (const float*)d_in[5];
  const float* wk = (const float*)d_in[6];
  const float* bk = (const float*)d_in[7];
  const float* wv = (const float*)d_in[8];
  const float* bv = (const float*)d_in[9];
  const float* wo = (const float*)d_in[10];
  const float* bo = (const float*)d_in[11];

  float* out  = (float*)d_out;
  float* attn = out + (size_t)B_ * S_ * D_;

  char* ws = (char*)d_ws;
  short* qkvc = (short*)ws;                        // bf16 casts of q,k,v: 3 x 8 MiB
  short* qh  = (short*)(ws + 25165824);            // bf16 [B][H][S][64]
  short* kh  = (short*)(ws + 33554432);
  short* vvt = (short*)(ws + 41943040);            // bf16 [B][H][64][S]
  short* ctx = (short*)(ws + 50331648);            // bf16 [B][S][512]
  short* wT  = (short*)(ws + 58720256);            // bf16 [512][512] x4: wq,wk,wv,wo transposed
  float* mb  = (float*)(ws + 58720256 + 4 * 524288);  // f32 [B][S] mask bias

  hipLaunchKernelGGL(k_prep, dim3(16, 16, 4), dim3(32, 8), 0, stream,
                     wq, wk, wv, wo, wT, wT + 262144, wT + 2 * 262144, wT + 3 * 262144);
  hipLaunchKernelGGL(k_cast, dim3(2048, 1, 3), dim3(256), 0, stream, q, k, v, qkvc);
  hipLaunchKernelGGL(k_maskbias, dim3(32), dim3(256), 0, stream, mask, mb);

  hipLaunchKernelGGL(k_gemm_qkv, dim3(64, 4, 3), dim3(256), 0, stream,
                     qkvc, wT, bq, bk, bv, qh, kh, vvt);

  hipLaunchKernelGGL(k_attn, dim3(16, 32), dim3(256), 0, stream, qh, kh, vvt, mb, attn, ctx);

  hipLaunchKernelGGL(k_gemm_out, dim3(64, 4), dim3(256), 0, stream, ctx, wT + 3 * 262144, bo, out);
}

// Round 6
// 252.465 us; speedup vs baseline: 1.1645x; 1.1645x over previous
//
#include <hip/hip_runtime.h>

#define B_ 4
#define S_ 2048
#define D_ 512
#define H_ 8
#define DP_ 64
#define NT_ (S_/64)

typedef __attribute__((ext_vector_type(4))) float f32x4;
typedef __attribute__((ext_vector_type(8))) short short8;

__device__ __forceinline__ short f2bf(float f){
  unsigned u = __float_as_uint(f);
  u += 0x7fff + ((u >> 16) & 1);   // round-to-nearest-even
  return (short)(u >> 16);
}

// element-offset swizzle for 64-element (128B) rows: XOR 8-elem granule with row&7
#define SWZ(r, kb) ((r)*64 + ((kb) ^ (((r)&7)<<3)))

#define WAITV(N) do{ asm volatile("s_waitcnt vmcnt(" #N ")" ::: "memory"); }while(0)
#define BAR() do{ __builtin_amdgcn_s_barrier(); __builtin_amdgcn_sched_barrier(0); }while(0)

// stage 64-elem-wide rows into linear LDS via global_load_lds, inverse-swizzled source
// (rule #21). NC global_load_lds ops per wave; tile bytes = NC * numWaves KB.
template<int NC>
__device__ __forceinline__ void stage_swz(const short* __restrict__ g, int rowStride,
                                          short* shbase, int w, int l){
  #pragma unroll
  for(int i = 0; i < NC; ++i){
    int byte = (w*NC + i)*1024 + l*16;
    int row = byte >> 7;
    int gs = ((byte >> 4) & 7) ^ (row & 7);
    const short* src = g + (size_t)row*rowStride + gs*8;
    __builtin_amdgcn_global_load_lds((const __attribute__((address_space(1))) void*)src,
        (__attribute__((address_space(3))) void*)(shbase + (w*NC + i)*512), 16, 0, 0);
  }
}

// ---------------- 4 weight transposes + cast to bf16 (z-sliced) ----------------
__global__ void k_prep(const float* __restrict__ w0, const float* __restrict__ w1,
                       const float* __restrict__ w2, const float* __restrict__ w3,
                       short* __restrict__ t0, short* __restrict__ t1,
                       short* __restrict__ t2, short* __restrict__ t3){
  __shared__ float t[32][33];
  const float* w = blockIdx.z == 0 ? w0 : blockIdx.z == 1 ? w1 : blockIdx.z == 2 ? w2 : w3;
  short* wt = blockIdx.z == 0 ? t0 : blockIdx.z == 1 ? t1 : blockIdx.z == 2 ? t2 : t3;
  int bx = blockIdx.x * 32, by = blockIdx.y * 32;
  int tx = threadIdx.x, ty = threadIdx.y;   // block (32,8)
  #pragma unroll
  for(int i = 0; i < 32; i += 8) t[ty + i][tx] = w[(by + ty + i) * D_ + bx + tx];
  __syncthreads();
  #pragma unroll
  for(int i = 0; i < 32; i += 8) wt[(bx + ty + i) * D_ + by + tx] = f2bf(t[tx][ty + i]);
}

// ---------------- cast q,k,v f32 -> bf16 (z 0..2); z==3: mask -> float bias ----------------
__global__ void k_cast(const float* __restrict__ q, const float* __restrict__ k,
                       const float* __restrict__ v, const int* __restrict__ mask,
                       short* __restrict__ dst, float* __restrict__ mb){
  if(blockIdx.z == 3){
    int i = blockIdx.x * 256 + threadIdx.x;
    if(i < B_ * S_) mb[i] = mask[i] ? -1.0e9f : 0.0f;
    return;
  }
  const float* s = blockIdx.z == 0 ? q : blockIdx.z == 1 ? k : v;
  short* d = dst + (size_t)blockIdx.z * (B_ * S_ * D_);
  int i = blockIdx.x * 256 + threadIdx.x;
  float4 a = ((const float4*)s)[i * 2];
  float4 b = ((const float4*)s)[i * 2 + 1];
  short8 o;
  o[0]=f2bf(a.x); o[1]=f2bf(a.y); o[2]=f2bf(a.z); o[3]=f2bf(a.w);
  o[4]=f2bf(b.x); o[5]=f2bf(b.y); o[6]=f2bf(b.z); o[7]=f2bf(b.w);
  ((short8*)d)[i] = o;
}

// ---------------- fused QKV GEMM: 128x128 tile, 4 waves, m97 single-buffer ----------------
__global__ __launch_bounds__(256) void k_gemm_qkv(const short* __restrict__ Xall,
        const short* __restrict__ WTall, const float* __restrict__ b0,
        const float* __restrict__ b1, const float* __restrict__ b2,
        short* __restrict__ qh, short* __restrict__ kh, short* __restrict__ vvt){
  __shared__ __align__(16) short As[8192];
  __shared__ __align__(16) short Bs[8192];
  const int z = blockIdx.z;
  const short* X  = Xall + (size_t)z * (B_*S_*D_);
  const short* WT = WTall + (size_t)z * (D_*D_);
  const float* bias = z==0 ? b0 : (z==1 ? b1 : b2);
  const int t = threadIdx.x, l = t & 63, w = t >> 6;
  const int lr = l & 15, lg = l >> 4;
  const int m0 = blockIdx.x * 128, n0 = blockIdx.y * 128;
  const int wr = w >> 1, wc = w & 1;
  const short* Xb = X + (size_t)m0 * D_;
  const short* Wb = WT + (size_t)n0 * D_;
  f32x4 acc[4][4] = {};
  for(int kt = 0; kt < D_ / 64; ++kt){
    stage_swz<4>(Xb + kt*64, D_, As, w, l);
    stage_swz<4>(Wb + kt*64, D_, Bs, w, l);
    __syncthreads();
    #pragma unroll
    for(int ks = 0; ks < 2; ++ks){
      const int kb = ks*32 + lg*8;
      short8 a[4], b[4];
      #pragma unroll
      for(int mt = 0; mt < 4; ++mt)
        a[mt] = *reinterpret_cast<const short8*>(&As[SWZ(wr*64 + mt*16 + lr, kb)]);
      #pragma unroll
      for(int nt = 0; nt < 4; ++nt)
        b[nt] = *reinterpret_cast<const short8*>(&Bs[SWZ(wc*64 + nt*16 + lr, kb)]);
      __builtin_amdgcn_s_setprio(1);
      #pragma unroll
      for(int mt = 0; mt < 4; ++mt)
        #pragma unroll
        for(int nt = 0; nt < 4; ++nt)
          acc[mt][nt] = __builtin_amdgcn_mfma_f32_16x16x32_bf16(a[mt], b[nt], acc[mt][nt], 0, 0, 0);
      __builtin_amdgcn_s_setprio(0);
    }
    __syncthreads();
  }
  #pragma unroll
  for(int mt = 0; mt < 4; ++mt){
    #pragma unroll
    for(int nt = 0; nt < 4; ++nt){
      const int n = n0 + wc*64 + nt*16 + lr;
      const int m4 = m0 + wr*64 + mt*16 + lg*4;
      float vals[4];
      #pragma unroll
      for(int r = 0; r < 4; ++r) vals[r] = acc[mt][nt][r] + bias[n];
      if(z == 2){
        short4 pv4;
        pv4.x = f2bf(vals[0]); pv4.y = f2bf(vals[1]); pv4.z = f2bf(vals[2]); pv4.w = f2bf(vals[3]);
        *reinterpret_cast<short4*>(&vvt[
            (((size_t)((m4 >> 11) * H_ + (n >> 6))) * DP_ + (n & 63)) * S_ + (m4 & 2047)]) = pv4;
      } else {
        short* dst = z == 0 ? qh : kh;
        #pragma unroll
        for(int r = 0; r < 4; ++r){
          int m = m4 + r;
          dst[(((size_t)((m >> 11) * H_ + (n >> 6))) * S_ + (m & 2047)) * DP_ + (n & 63)] = f2bf(vals[r]);
        }
      }
    }
  }
}

// ---------------- out GEMM: ctx[8192,512]bf16 @ woT + bo -> f32 ----------------
__global__ __launch_bounds__(256) void k_gemm_out(const short* __restrict__ X,
        const short* __restrict__ WT, const float* __restrict__ bias,
        float* __restrict__ Out){
  __shared__ __align__(16) short As[8192];
  __shared__ __align__(16) short Bs[8192];
  const int t = threadIdx.x, l = t & 63, w = t >> 6;
  const int lr = l & 15, lg = l >> 4;
  const int m0 = blockIdx.x * 128, n0 = blockIdx.y * 128;
  const int wr = w >> 1, wc = w & 1;
  const short* Xb = X + (size_t)m0 * D_;
  const short* Wb = WT + (size_t)n0 * D_;
  f32x4 acc[4][4] = {};
  for(int kt = 0; kt < D_ / 64; ++kt){
    stage_swz<4>(Xb + kt*64, D_, As, w, l);
    stage_swz<4>(Wb + kt*64, D_, Bs, w, l);
    __syncthreads();
    #pragma unroll
    for(int ks = 0; ks < 2; ++ks){
      const int kb = ks*32 + lg*8;
      short8 a[4], b[4];
      #pragma unroll
      for(int mt = 0; mt < 4; ++mt)
        a[mt] = *reinterpret_cast<const short8*>(&As[SWZ(wr*64 + mt*16 + lr, kb)]);
      #pragma unroll
      for(int nt = 0; nt < 4; ++nt)
        b[nt] = *reinterpret_cast<const short8*>(&Bs[SWZ(wc*64 + nt*16 + lr, kb)]);
      __builtin_amdgcn_s_setprio(1);
      #pragma unroll
      for(int mt = 0; mt < 4; ++mt)
        #pragma unroll
        for(int nt = 0; nt < 4; ++nt)
          acc[mt][nt] = __builtin_amdgcn_mfma_f32_16x16x32_bf16(a[mt], b[nt], acc[mt][nt], 0, 0, 0);
      __builtin_amdgcn_s_setprio(0);
    }
    __syncthreads();
  }
  #pragma unroll
  for(int mt = 0; mt < 4; ++mt){
    #pragma unroll
    for(int nt = 0; nt < 4; ++nt){
      const int n = n0 + wc*64 + nt*16 + lr;
      const int m4 = m0 + wr*64 + mt*16 + lg*4;
      #pragma unroll
      for(int r = 0; r < 4; ++r)
        Out[(size_t)(m4 + r) * D_ + n] = acc[mt][nt][r] + bias[n];
    }
  }
}

// ---------------- fused attention ----------------
// 8 waves, q-tile 128 (16 q-rows/wave). Swapped QK^T: lane -> (q=lr, k=lg*4+r).
// Counted-vmcnt with stage-issued-AFTER-barrier (no buffer race):
//   pass A: K ring-of-3, WAITV(1) steady / WAITV(0) tail
//   pass B: K,V dbuf-2, WAITV(0) at kt=0 / WAITV(4) steady (4 = attn stores of prev iter)
// LDS shorts: staging [0,16384) (A: ring bufs at 0/4096/8192; B: kb 0/4096, vb 8192/12288),
//             Q-then-P [16384,24576), mask f32 [24576,28672)  => 56 KB, 2 blocks/CU
__global__ __launch_bounds__(512, 4) void k_attn(const short* __restrict__ qh,
                                                 const short* __restrict__ kh,
                                                 const short* __restrict__ vt,
                                                 const float* __restrict__ mb,
                                                 float* __restrict__ attn,
                                                 short* __restrict__ ctx){
  __shared__ __align__(16) short Sh[28672];
  const int t = threadIdx.x, l = t & 63, w = t >> 6;
  const int lr = l & 15, lg = l >> 4;
  // XCD-aware bijective swizzle: 512 wgs; XCD x gets 4 bh x 16 q-tiles (2MB K/V per L2)
  int lin = blockIdx.y * 16 + blockIdx.x;
  int sw = (lin & 7) * 64 + (lin >> 3);
  const int bh = sw >> 4, b = bh >> 3, h = bh & 7;
  const int q0 = (sw & 15) * 128;
  const short* Qb = qh + (size_t)bh * S_ * DP_ + (size_t)q0 * DP_;
  const short* Kb = kh + (size_t)bh * S_ * DP_;
  const short* Vtb = vt + (size_t)bh * DP_ * S_;
  const float* Mbb = mb + b * S_;
  float* Mlds = (float*)(Sh + 24576);
  const float scale = 0.125f;

  // prologue: Q (16KB swz, 2 ops), mask (8KB linear, 1 op), K0->buf0, K1->buf1
  stage_swz<2>(Qb, DP_, Sh + 16384, w, l);
  __builtin_amdgcn_global_load_lds(
      (const __attribute__((address_space(1))) void*)(Mbb + w*256 + l*4),
      (__attribute__((address_space(3))) void*)(Mlds + w*256 + l*4), 16, 0, 0);
  stage_swz<1>(Kb, DP_, Sh, w, l);
  stage_swz<1>(Kb + 4096, DP_, Sh + 4096, w, l);
  WAITV(2); BAR();                                  // Q+mask retired (oldest 3 of 5); K0,K1 in flight
  short8 bq0, bq1;
  {
    int r = w * 16 + lr;
    bq0 = *reinterpret_cast<const short8*>(&Sh[16384 + SWZ(r, lg * 8)]);
    bq1 = *reinterpret_cast<const short8*>(&Sh[16384 + SWZ(r, 32 + lg * 8)]);
  }

  // ---------------- pass A: row sums ----------------
  float ps = 0.f;
  for(int kt = 0; kt < NT_; ++kt){
    // queue: K_kt, K_{kt+1}(if any). WAITV(1) retires K_kt; tail uses WAITV(0).
    if(kt < NT_ - 1){ WAITV(1); } else { WAITV(0); }
    BAR();
    // stage AFTER barrier: buf (kt+2)%3 == (kt-1)%3, last read before this barrier
    if(kt + 2 < NT_)
      stage_swz<1>(Kb + (size_t)(kt + 2) * 4096, DP_, Sh + ((kt + 2) % 3) * 4096, w, l);
    const short* Kc = Sh + (kt % 3) * 4096;
    const float* Ml = Mlds + kt * 64;
    #pragma unroll
    for(int st = 0; st < 4; ++st){
      const float4 mv = ((const float4*)Ml)[st * 4 + lg];
      short8 ak0 = *reinterpret_cast<const short8*>(&Kc[SWZ(st * 16 + lr, lg * 8)]);
      short8 ak1 = *reinterpret_cast<const short8*>(&Kc[SWZ(st * 16 + lr, 32 + lg * 8)]);
      __builtin_amdgcn_s_setprio(1);
      f32x4 c = {};
      c = __builtin_amdgcn_mfma_f32_16x16x32_bf16(ak0, bq0, c, 0, 0, 0);
      c = __builtin_amdgcn_mfma_f32_16x16x32_bf16(ak1, bq1, c, 0, 0, 0);
      __builtin_amdgcn_s_setprio(0);
      ps += __expf(__builtin_fmaf(c[0], scale, mv.x));
      ps += __expf(__builtin_fmaf(c[1], scale, mv.y));
      ps += __expf(__builtin_fmaf(c[2], scale, mv.z));
      ps += __expf(__builtin_fmaf(c[3], scale, mv.w));
    }
  }
  // prefetch pass-B tile 0 immediately (kb0: last read tile 30 before BAR(31);
  // vb0 = ring buf2: last read tile 29. All waves passed BAR(31) => safe.)
  stage_swz<1>(Kb, DP_, Sh, w, l);
  stage_swz<1>(Vtb, S_, Sh + 8192, w, l);
  ps += __shfl_xor(ps, 16, 64);
  ps += __shfl_xor(ps, 32, 64);
  const float rinv = 1.f / ps;

  // ---------------- pass B: normalized attn write + PV ----------------
  f32x4 o[4] = {};
  short* Pw = Sh + 16384 + w * 1024;                // per-wave 16x64 P (reuses Q region)
  for(int kt = 0; kt < NT_; ++kt){
    // queue at wait: K_kt,V_kt then stores_{kt-1}(4). WAITV(4) retires K_kt,V_kt.
    if(kt == 0){ WAITV(0); } else { WAITV(4); }
    BAR();
    if(kt + 1 < NT_){
      stage_swz<1>(Kb + (size_t)(kt + 1) * 4096, DP_, Sh + ((kt + 1) & 1) * 4096, w, l);
      stage_swz<1>(Vtb + (size_t)(kt + 1) * 64, S_, Sh + 8192 + ((kt + 1) & 1) * 4096, w, l);
    }
    const short* Kc = Sh + (kt & 1) * 4096;
    const short* Vc = Sh + 8192 + (kt & 1) * 4096;
    const float* Ml = Mlds + kt * 64;
    #pragma unroll
    for(int st = 0; st < 4; ++st){
      const float4 mv = ((const float4*)Ml)[st * 4 + lg];
      short8 ak0 = *reinterpret_cast<const short8*>(&Kc[SWZ(st * 16 + lr, lg * 8)]);
      short8 ak1 = *reinterpret_cast<const short8*>(&Kc[SWZ(st * 16 + lr, 32 + lg * 8)]);
      __builtin_amdgcn_s_setprio(1);
      f32x4 c = {};
      c = __builtin_amdgcn_mfma_f32_16x16x32_bf16(ak0, bq0, c, 0, 0, 0);
      c = __builtin_amdgcn_mfma_f32_16x16x32_bf16(ak1, bq1, c, 0, 0, 0);
      __builtin_amdgcn_s_setprio(0);
      float4 pw;
      pw.x = __expf(__builtin_fmaf(c[0], scale, mv.x)) * rinv;
      pw.y = __expf(__builtin_fmaf(c[1], scale, mv.y)) * rinv;
      pw.z = __expf(__builtin_fmaf(c[2], scale, mv.z)) * rinv;
      pw.w = __expf(__builtin_fmaf(c[3], scale, mv.w)) * rinv;
      const int q = q0 + w * 16 + lr;
      *reinterpret_cast<float4*>(&attn[((size_t)bh * S_ + q) * S_ + kt * 64 + st * 16 + lg * 4]) = pw;
      short4 pb;
      pb.x = f2bf(pw.x); pb.y = f2bf(pw.y); pb.z = f2bf(pw.z); pb.w = f2bf(pw.w);
      *reinterpret_cast<short4*>(&Pw[SWZ(lr, st * 16 + lg * 4)]) = pb;
    }
    #pragma unroll
    for(int ks = 0; ks < 2; ++ks){
      short8 pa = *reinterpret_cast<const short8*>(&Pw[SWZ(lr, ks * 32 + lg * 8)]);
      __builtin_amdgcn_s_setprio(1);
      #pragma unroll
      for(int dt = 0; dt < 4; ++dt){
        short8 vb = *reinterpret_cast<const short8*>(&Vc[SWZ(dt * 16 + lr, ks * 32 + lg * 8)]);
        o[dt] = __builtin_amdgcn_mfma_f32_16x16x32_bf16(pa, vb, o[dt], 0, 0, 0);
      }
      __builtin_amdgcn_s_setprio(0);
    }
  }
  // write context (head-merged bf16 [B][S][512]); o already normalized
  #pragma unroll
  for(int dt = 0; dt < 4; ++dt){
    #pragma unroll
    for(int r = 0; r < 4; ++r){
      int q = q0 + w * 16 + lg * 4 + r;
      int dd = h * 64 + dt * 16 + lr;
      ctx[((size_t)b * S_ + q) * D_ + dd] = f2bf(o[dt][r]);
    }
  }
}

extern "C" void kernel_launch(void* const* d_in, const int* in_sizes, int n_in,
                              void* d_out, int out_size, void* d_ws, size_t ws_size,
                              hipStream_t stream){
  const float* q  = (const float*)d_in[0];
  const float* k  = (const float*)d_in[1];
  const float* v  = (const float*)d_in[2];
  const int* mask = (const int*)d_in[3];
  const float* wq = (const float*)d_in[4];
  const float* bq = (const float*)d_in[5];
  const float* wk = (const float*)d_in[6];
  const float* bk = (const float*)d_in[7];
  const float* wv = (const float*)d_in[8];
  const float* bv = (const float*)d_in[9];
  const float* wo = (const float*)d_in[10];
  const float* bo = (const float*)d_in[11];

  float* out  = (float*)d_out;
  float* attn = out + (size_t)B_ * S_ * D_;

  char* ws = (char*)d_ws;
  short* qkvc = (short*)ws;                        // bf16 casts of q,k,v: 3 x 8 MiB
  short* qh  = (short*)(ws + 25165824);            // bf16 [B][H][S][64]
  short* kh  = (short*)(ws + 33554432);
  short* vvt = (short*)(ws + 41943040);            // bf16 [B][H][64][S]
  short* ctx = (short*)(ws + 50331648);            // bf16 [B][S][512]
  short* wT  = (short*)(ws + 58720256);            // bf16 [512][512] x4: wq,wk,wv,wo transposed
  float* mb  = (float*)(ws + 58720256 + 4 * 524288);  // f32 [B][S] mask bias

  hipLaunchKernelGGL(k_prep, dim3(16, 16, 4), dim3(32, 8), 0, stream,
                     wq, wk, wv, wo, wT, wT + 262144, wT + 2 * 262144, wT + 3 * 262144);
  hipLaunchKernelGGL(k_cast, dim3(2048, 1, 4), dim3(256), 0, stream, q, k, v, mask, qkvc, mb);

  hipLaunchKernelGGL(k_gemm_qkv, dim3(64, 4, 3), dim3(256), 0, stream,
                     qkvc, wT, bq, bk, bv, qh, kh, vvt);

  hipLaunchKernelGGL(k_attn, dim3(16, 32), dim3(512), 0, stream, qh, kh, vvt, mb, attn, ctx);

  hipLaunchKernelGGL(k_gemm_out, dim3(64, 4), dim3(256), 0, stream, ctx, wT + 3 * 262144, bo, out);
}

// Round 7
// 250.752 us; speedup vs baseline: 1.1724x; 1.0068x over previous
//
#include <hip/hip_runtime.h>

#define B_ 4
#define S_ 2048
#define D_ 512
#define H_ 8
#define DP_ 64
#define NT_ (S_/64)

typedef __attribute__((ext_vector_type(4))) float f32x4;
typedef __attribute__((ext_vector_type(8))) short short8;
typedef __attribute__((ext_vector_type(4))) int i32x4;

__device__ __forceinline__ short f2bf(float f){
  unsigned u = __float_as_uint(f);
  u += 0x7fff + ((u >> 16) & 1);   // round-to-nearest-even
  return (short)(u >> 16);
}

__device__ __forceinline__ int cvtpk(float lo, float hi){
  int r;
  asm("v_cvt_pk_bf16_f32 %0, %1, %2" : "=v"(r) : "v"(lo), "v"(hi));
  return r;
}

// GEMM swizzle (old): XOR 8-elem granule with row&7
#define SWZ(r, kb) ((r)*64 + ((kb) ^ (((r)&7)<<3)))
// attn swizzle: f(row) = (row&3) | ((row>>3)&1)<<2  (2-way for both linear and
// g_st-permuted 16-row reads)
#define F2(r) ((((r)&3)) | ((((r)>>3)&1)<<2))
#define SWZ2(r, kb) ((r)*64 + ((kb) ^ (F2(r)<<3)))

#define WAITV(N) do{ asm volatile("s_waitcnt vmcnt(" #N ")" ::: "memory"); }while(0)
#define BAR() do{ __builtin_amdgcn_s_barrier(); __builtin_amdgcn_sched_barrier(0); }while(0)

// stage 64-elem-wide rows into linear LDS via global_load_lds, inverse-swizzled source
template<int NC>
__device__ __forceinline__ void stage_swz(const short* __restrict__ g, int rowStride,
                                          short* shbase, int w, int l){
  #pragma unroll
  for(int i = 0; i < NC; ++i){
    int byte = (w*NC + i)*1024 + l*16;
    int row = byte >> 7;
    int gs = ((byte >> 4) & 7) ^ (row & 7);
    const short* src = g + (size_t)row*rowStride + gs*8;
    __builtin_amdgcn_global_load_lds((const __attribute__((address_space(1))) void*)src,
        (__attribute__((address_space(3))) void*)(shbase + (w*NC + i)*512), 16, 0, 0);
  }
}
template<int NC>
__device__ __forceinline__ void stage_swz2(const short* __restrict__ g, int rowStride,
                                           short* shbase, int w, int l){
  #pragma unroll
  for(int i = 0; i < NC; ++i){
    int byte = (w*NC + i)*1024 + l*16;
    int row = byte >> 7;
    int gs = ((byte >> 4) & 7) ^ F2(row);
    const short* src = g + (size_t)row*rowStride + gs*8;
    __builtin_amdgcn_global_load_lds((const __attribute__((address_space(1))) void*)src,
        (__attribute__((address_space(3))) void*)(shbase + (w*NC + i)*512), 16, 0, 0);
  }
}

// ---------------- fused pre-pass: weight transposes + qkv cast + mask bias ----------------
// blocks [0,1024): 4 weight transposes; [1024,7168): q/k/v cast; [7168,7200): mask
__global__ __launch_bounds__(256) void k_pre(const float* __restrict__ q,
        const float* __restrict__ k, const float* __restrict__ v,
        const int* __restrict__ mask,
        const float* __restrict__ w0, const float* __restrict__ w1,
        const float* __restrict__ w2, const float* __restrict__ w3,
        short* __restrict__ wT, short* __restrict__ qkvc, float* __restrict__ mb){
  __shared__ float tt[32][33];
  const int bi = blockIdx.x, t = threadIdx.x;
  if(bi < 1024){
    const int z = bi >> 8;
    const float* w = z == 0 ? w0 : z == 1 ? w1 : z == 2 ? w2 : w3;
    short* wt = wT + z * 262144;
    const int bxy = bi & 255;
    const int bx = (bxy & 15) * 32, by = (bxy >> 4) * 32;
    const int tx = t & 31, ty = t >> 5;
    #pragma unroll
    for(int i = 0; i < 32; i += 8) tt[ty + i][tx] = w[(by + ty + i) * D_ + bx + tx];
    __syncthreads();
    #pragma unroll
    for(int i = 0; i < 32; i += 8) wt[(bx + ty + i) * D_ + by + tx] = f2bf(tt[tx][ty + i]);
  } else if(bi < 7168){
    const int ci = bi - 1024;
    const int z = ci >> 11;
    const float* s = z == 0 ? q : z == 1 ? k : v;
    short* d = qkvc + (size_t)z * (B_ * S_ * D_);
    int i = (ci & 2047) * 256 + t;
    float4 a = ((const float4*)s)[i * 2];
    float4 b = ((const float4*)s)[i * 2 + 1];
    short8 o;
    o[0]=f2bf(a.x); o[1]=f2bf(a.y); o[2]=f2bf(a.z); o[3]=f2bf(a.w);
    o[4]=f2bf(b.x); o[5]=f2bf(b.y); o[6]=f2bf(b.z); o[7]=f2bf(b.w);
    ((short8*)d)[i] = o;
  } else {
    int i = (bi - 7168) * 256 + t;
    mb[i] = mask[i] ? -1.0e9f : 0.0f;
  }
}

// ---------------- fused QKV GEMM: 128x128 tile, 4 waves, m97 single-buffer ----------------
__global__ __launch_bounds__(256) void k_gemm_qkv(const short* __restrict__ Xall,
        const short* __restrict__ WTall, const float* __restrict__ b0,
        const float* __restrict__ b1, const float* __restrict__ b2,
        short* __restrict__ qh, short* __restrict__ kh, short* __restrict__ vvt){
  __shared__ __align__(16) short As[8192];
  __shared__ __align__(16) short Bs[8192];
  const int z = blockIdx.z;
  const short* X  = Xall + (size_t)z * (B_*S_*D_);
  const short* WT = WTall + (size_t)z * (D_*D_);
  const float* bias = z==0 ? b0 : (z==1 ? b1 : b2);
  const int t = threadIdx.x, l = t & 63, w = t >> 6;
  const int lr = l & 15, lg = l >> 4;
  const int m0 = blockIdx.x * 128, n0 = blockIdx.y * 128;
  const int wr = w >> 1, wc = w & 1;
  const short* Xb = X + (size_t)m0 * D_;
  const short* Wb = WT + (size_t)n0 * D_;
  f32x4 acc[4][4] = {};
  for(int kt = 0; kt < D_ / 64; ++kt){
    stage_swz<4>(Xb + kt*64, D_, As, w, l);
    stage_swz<4>(Wb + kt*64, D_, Bs, w, l);
    __syncthreads();
    #pragma unroll
    for(int ks = 0; ks < 2; ++ks){
      const int kb = ks*32 + lg*8;
      short8 a[4], b[4];
      #pragma unroll
      for(int mt = 0; mt < 4; ++mt)
        a[mt] = *reinterpret_cast<const short8*>(&As[SWZ(wr*64 + mt*16 + lr, kb)]);
      #pragma unroll
      for(int nt = 0; nt < 4; ++nt)
        b[nt] = *reinterpret_cast<const short8*>(&Bs[SWZ(wc*64 + nt*16 + lr, kb)]);
      __builtin_amdgcn_s_setprio(1);
      #pragma unroll
      for(int mt = 0; mt < 4; ++mt)
        #pragma unroll
        for(int nt = 0; nt < 4; ++nt)
          acc[mt][nt] = __builtin_amdgcn_mfma_f32_16x16x32_bf16(a[mt], b[nt], acc[mt][nt], 0, 0, 0);
      __builtin_amdgcn_s_setprio(0);
    }
    __syncthreads();
  }
  #pragma unroll
  for(int mt = 0; mt < 4; ++mt){
    #pragma unroll
    for(int nt = 0; nt < 4; ++nt){
      const int n = n0 + wc*64 + nt*16 + lr;
      const int m4 = m0 + wr*64 + mt*16 + lg*4;
      float vals[4];
      #pragma unroll
      for(int r = 0; r < 4; ++r) vals[r] = acc[mt][nt][r] + bias[n];
      if(z == 2){
        short4 pv4;
        pv4.x = f2bf(vals[0]); pv4.y = f2bf(vals[1]); pv4.z = f2bf(vals[2]); pv4.w = f2bf(vals[3]);
        *reinterpret_cast<short4*>(&vvt[
            (((size_t)((m4 >> 11) * H_ + (n >> 6))) * DP_ + (n & 63)) * S_ + (m4 & 2047)]) = pv4;
      } else {
        short* dst = z == 0 ? qh : kh;
        #pragma unroll
        for(int r = 0; r < 4; ++r){
          int m = m4 + r;
          dst[(((size_t)((m >> 11) * H_ + (n >> 6))) * S_ + (m & 2047)) * DP_ + (n & 63)] = f2bf(vals[r]);
        }
      }
    }
  }
}

// ---------------- out GEMM: ctx[8192,512]bf16 @ woT + bo -> f32 ----------------
__global__ __launch_bounds__(256) void k_gemm_out(const short* __restrict__ X,
        const short* __restrict__ WT, const float* __restrict__ bias,
        float* __restrict__ Out){
  __shared__ __align__(16) short As[8192];
  __shared__ __align__(16) short Bs[8192];
  const int t = threadIdx.x, l = t & 63, w = t >> 6;
  const int lr = l & 15, lg = l >> 4;
  const int m0 = blockIdx.x * 128, n0 = blockIdx.y * 128;
  const int wr = w >> 1, wc = w & 1;
  const short* Xb = X + (size_t)m0 * D_;
  const short* Wb = WT + (size_t)n0 * D_;
  f32x4 acc[4][4] = {};
  for(int kt = 0; kt < D_ / 64; ++kt){
    stage_swz<4>(Xb + kt*64, D_, As, w, l);
    stage_swz<4>(Wb + kt*64, D_, Bs, w, l);
    __syncthreads();
    #pragma unroll
    for(int ks = 0; ks < 2; ++ks){
      const int kb = ks*32 + lg*8;
      short8 a[4], b[4];
      #pragma unroll
      for(int mt = 0; mt < 4; ++mt)
        a[mt] = *reinterpret_cast<const short8*>(&As[SWZ(wr*64 + mt*16 + lr, kb)]);
      #pragma unroll
      for(int nt = 0; nt < 4; ++nt)
        b[nt] = *reinterpret_cast<const short8*>(&Bs[SWZ(wc*64 + nt*16 + lr, kb)]);
      __builtin_amdgcn_s_setprio(1);
      #pragma unroll
      for(int mt = 0; mt < 4; ++mt)
        #pragma unroll
        for(int nt = 0; nt < 4; ++nt)
          acc[mt][nt] = __builtin_amdgcn_mfma_f32_16x16x32_bf16(a[mt], b[nt], acc[mt][nt], 0, 0, 0);
      __builtin_amdgcn_s_setprio(0);
    }
    __syncthreads();
  }
  #pragma unroll
  for(int mt = 0; mt < 4; ++mt){
    #pragma unroll
    for(int nt = 0; nt < 4; ++nt){
      const int n = n0 + wc*64 + nt*16 + lr;
      const int m4 = m0 + wr*64 + mt*16 + lg*4;
      #pragma unroll
      for(int r = 0; r < 4; ++r)
        Out[(size_t)(m4 + r) * D_ + n] = acc[mt][nt][r] + bias[n];
    }
  }
}

// ---------------- fused attention ----------------
// 8 waves, q-tile 128. Swapped QK^T with PERMUTED A-rows g_st(i)=(i>>2)*8+(st&1)*4+(i&3)+(st>>1)*32
// so lane (q=lr,lg) ends holding P[q][k=32ks+lg*8+0..7] -> PV A-fragment built in-register
// via v_cvt_pk_bf16_f32 (no P LDS roundtrip, no cross-lane ops).
// Counted-vmcnt (R6 protocol): pass A K ring-3 WAITV(1)/0; pass B K,V dbuf WAITV(4), stage after BAR.
// LDS shorts: K [0,8192) (A: ring 0/4096/8192), V dbuf [8192,16384), Q [16384,24576),
//             mask f32 [24576,28672)  => 56 KB, 2 blocks/CU
__global__ __launch_bounds__(512, 4) void k_attn(const short* __restrict__ qh,
                                                 const short* __restrict__ kh,
                                                 const short* __restrict__ vt,
                                                 const float* __restrict__ mb,
                                                 float* __restrict__ attn,
                                                 short* __restrict__ ctx){
  __shared__ __align__(16) short Sh[28672];
  const int t = threadIdx.x, l = t & 63, w = t >> 6;
  const int lr = l & 15, lg = l >> 4;
  // XCD-aware bijective swizzle: 512 wgs; XCD x gets 4 bh x 16 q-tiles
  int lin = blockIdx.y * 16 + blockIdx.x;
  int sw = (lin & 7) * 64 + (lin >> 3);
  const int bh = sw >> 4, b = bh >> 3, h = bh & 7;
  const int q0 = (sw & 15) * 128;
  const short* Qb = qh + (size_t)bh * S_ * DP_ + (size_t)q0 * DP_;
  const short* Kb = kh + (size_t)bh * S_ * DP_;
  const short* Vtb = vt + (size_t)bh * DP_ * S_;
  const float* Mbb = mb + b * S_;
  float* Mlds = (float*)(Sh + 24576);
  const float scale = 0.125f;

  // prologue: Q (16KB swz2, 2 ops), mask (8KB linear, 1 op), K0->buf0, K1->buf1
  stage_swz2<2>(Qb, DP_, Sh + 16384, w, l);
  __builtin_amdgcn_global_load_lds(
      (const __attribute__((address_space(1))) void*)(Mbb + w*256 + l*4),
      (__attribute__((address_space(3))) void*)(Mlds + w*256 + l*4), 16, 0, 0);
  stage_swz2<1>(Kb, DP_, Sh, w, l);
  stage_swz2<1>(Kb + 4096, DP_, Sh + 4096, w, l);
  WAITV(2); BAR();                                  // Q+mask retired; K0,K1 in flight
  short8 bq0, bq1;
  {
    int r = w * 16 + lr;
    bq0 = *reinterpret_cast<const short8*>(&Sh[16384 + SWZ2(r, lg * 8)]);
    bq1 = *reinterpret_cast<const short8*>(&Sh[16384 + SWZ2(r, 32 + lg * 8)]);
  }

  // ---------------- pass A: row sums (linear rows; sum is permutation-invariant) ----------------
  float ps = 0.f;
  for(int kt = 0; kt < NT_; ++kt){
    if(kt < NT_ - 1){ WAITV(1); } else { WAITV(0); }
    BAR();
    if(kt + 2 < NT_)
      stage_swz2<1>(Kb + (size_t)(kt + 2) * 4096, DP_, Sh + ((kt + 2) % 3) * 4096, w, l);
    const short* Kc = Sh + (kt % 3) * 4096;
    const float* Ml = Mlds + kt * 64;
    #pragma unroll
    for(int st = 0; st < 4; ++st){
      const float4 mv = *(const float4*)&Ml[st * 16 + lg * 4];
      short8 ak0 = *reinterpret_cast<const short8*>(&Kc[SWZ2(st * 16 + lr, lg * 8)]);
      short8 ak1 = *reinterpret_cast<const short8*>(&Kc[SWZ2(st * 16 + lr, 32 + lg * 8)]);
      __builtin_amdgcn_s_setprio(1);
      f32x4 c = {};
      c = __builtin_amdgcn_mfma_f32_16x16x32_bf16(ak0, bq0, c, 0, 0, 0);
      c = __builtin_amdgcn_mfma_f32_16x16x32_bf16(ak1, bq1, c, 0, 0, 0);
      __builtin_amdgcn_s_setprio(0);
      ps += __expf(__builtin_fmaf(c[0], scale, mv.x));
      ps += __expf(__builtin_fmaf(c[1], scale, mv.y));
      ps += __expf(__builtin_fmaf(c[2], scale, mv.z));
      ps += __expf(__builtin_fmaf(c[3], scale, mv.w));
    }
  }
  // prefetch pass-B tile 0 (buffers last read >=1 barrier ago for every wave)
  stage_swz2<1>(Kb, DP_, Sh, w, l);
  stage_swz2<1>(Vtb, S_, Sh + 8192, w, l);
  ps += __shfl_xor(ps, 16, 64);
  ps += __shfl_xor(ps, 32, 64);
  const float rinv = 1.f / ps;

  // ---------------- pass B: attn write + in-register PV ----------------
  f32x4 o[4] = {};
  const int grow = ((lr >> 2) << 3) + (lr & 3);    // g_st row base for this lane
  for(int kt = 0; kt < NT_; ++kt){
    if(kt == 0){ WAITV(0); } else { WAITV(4); }
    BAR();
    if(kt + 1 < NT_){
      stage_swz2<1>(Kb + (size_t)(kt + 1) * 4096, DP_, Sh + ((kt + 1) & 1) * 4096, w, l);
      stage_swz2<1>(Vtb + (size_t)(kt + 1) * 64, S_, Sh + 8192 + ((kt + 1) & 1) * 4096, w, l);
    }
    const short* Kc = Sh + (kt & 1) * 4096;
    const short* Vc = Sh + 8192 + (kt & 1) * 4096;
    const float* Ml = Mlds + kt * 64;
    const int q = q0 + w * 16 + lr;
    i32x4 pav[2];
    #pragma unroll
    for(int st = 0; st < 4; ++st){
      const int ks = st >> 1, h4 = st & 1;
      const int row = grow + h4 * 4 + ks * 32;     // permuted A rows
      const int mcol = ks * 32 + h4 * 4 + lg * 8;  // k-columns this lane produces
      const float4 mv = *(const float4*)&Ml[mcol];
      short8 ak0 = *reinterpret_cast<const short8*>(&Kc[SWZ2(row, lg * 8)]);
      short8 ak1 = *reinterpret_cast<const short8*>(&Kc[SWZ2(row, 32 + lg * 8)]);
      __builtin_amdgcn_s_setprio(1);
      f32x4 c = {};
      c = __builtin_amdgcn_mfma_f32_16x16x32_bf16(ak0, bq0, c, 0, 0, 0);
      c = __builtin_amdgcn_mfma_f32_16x16x32_bf16(ak1, bq1, c, 0, 0, 0);
      __builtin_amdgcn_s_setprio(0);
      float4 pw;
      pw.x = __expf(__builtin_fmaf(c[0], scale, mv.x)) * rinv;
      pw.y = __expf(__builtin_fmaf(c[1], scale, mv.y)) * rinv;
      pw.z = __expf(__builtin_fmaf(c[2], scale, mv.z)) * rinv;
      pw.w = __expf(__builtin_fmaf(c[3], scale, mv.w)) * rinv;
      *reinterpret_cast<float4*>(&attn[((size_t)bh * S_ + q) * S_ + kt * 64 + mcol]) = pw;
      pav[ks][h4 * 2 + 0] = cvtpk(pw.x, pw.y);     // bf16 pair (k, k+1)
      pav[ks][h4 * 2 + 1] = cvtpk(pw.z, pw.w);     // bf16 pair (k+2, k+3)
    }
    #pragma unroll
    for(int ks = 0; ks < 2; ++ks){
      short8 pa = __builtin_bit_cast(short8, pav[ks]);
      __builtin_amdgcn_s_setprio(1);
      #pragma unroll
      for(int dt = 0; dt < 4; ++dt){
        short8 vb = *reinterpret_cast<const short8*>(&Vc[SWZ2(dt * 16 + lr, ks * 32 + lg * 8)]);
        o[dt] = __builtin_amdgcn_mfma_f32_16x16x32_bf16(pa, vb, o[dt], 0, 0, 0);
      }
      __builtin_amdgcn_s_setprio(0);
    }
  }
  // write context (head-merged bf16 [B][S][512]); o already normalized
  #pragma unroll
  for(int dt = 0; dt < 4; ++dt){
    #pragma unroll
    for(int r = 0; r < 4; ++r){
      int q = q0 + w * 16 + lg * 4 + r;
      int dd = h * 64 + dt * 16 + lr;
      ctx[((size_t)b * S_ + q) * D_ + dd] = f2bf(o[dt][r]);
    }
  }
}

extern "C" void kernel_launch(void* const* d_in, const int* in_sizes, int n_in,
                              void* d_out, int out_size, void* d_ws, size_t ws_size,
                              hipStream_t stream){
  const float* q  = (const float*)d_in[0];
  const float* k  = (const float*)d_in[1];
  const float* v  = (const float*)d_in[2];
  const int* mask = (const int*)d_in[3];
  const float* wq = (const float*)d_in[4];
  const float* bq = (const float*)d_in[5];
  const float* wk = (const float*)d_in[6];
  const float* bk = (const float*)d_in[7];
  const float* wv = (const float*)d_in[8];
  const float* bv = (const float*)d_in[9];
  const float* wo = (const float*)d_in[10];
  const float* bo = (const float*)d_in[11];

  float* out  = (float*)d_out;
  float* attn = out + (size_t)B_ * S_ * D_;

  char* ws = (char*)d_ws;
  short* qkvc = (short*)ws;                        // bf16 casts of q,k,v: 3 x 8 MiB
  short* qh  = (short*)(ws + 25165824);            // bf16 [B][H][S][64]
  short* kh  = (short*)(ws + 33554432);
  short* vvt = (short*)(ws + 41943040);            // bf16 [B][H][64][S]
  short* ctx = (short*)(ws + 50331648);            // bf16 [B][S][512]
  short* wT  = (short*)(ws + 58720256);            // bf16 [512][512] x4 transposed
  float* mb  = (float*)(ws + 58720256 + 4 * 524288);  // f32 [B][S] mask bias

  hipLaunchKernelGGL(k_pre, dim3(7200), dim3(256), 0, stream,
                     q, k, v, mask, wq, wk, wv, wo, wT, qkvc, mb);

  hipLaunchKernelGGL(k_gemm_qkv, dim3(64, 4, 3), dim3(256), 0, stream,
                     qkvc, wT, bq, bk, bv, qh, kh, vvt);

  hipLaunchKernelGGL(k_attn, dim3(16, 32), dim3(512), 0, stream, qh, kh, vvt, mb, attn, ctx);

  hipLaunchKernelGGL(k_gemm_out, dim3(64, 4), dim3(256), 0, stream, ctx, wT + 3 * 262144, bo, out);
}

// Round 8
// 244.416 us; speedup vs baseline: 1.2028x; 1.0259x over previous
//
#include <hip/hip_runtime.h>

#define B_ 4
#define S_ 2048
#define D_ 512
#define H_ 8
#define DP_ 64
#define NT_ (S_/64)

typedef __attribute__((ext_vector_type(4))) float f32x4;
typedef __attribute__((ext_vector_type(8))) short short8;
typedef __attribute__((ext_vector_type(4))) int i32x4;

__device__ __forceinline__ short f2bf(float f){
  unsigned u = __float_as_uint(f);
  u += 0x7fff + ((u >> 16) & 1);   // round-to-nearest-even
  return (short)(u >> 16);
}

__device__ __forceinline__ int cvtpk(float lo, float hi){
  int r;
  asm("v_cvt_pk_bf16_f32 %0, %1, %2" : "=v"(r) : "v"(lo), "v"(hi));
  return r;
}

// GEMM swizzle: XOR 8-elem granule with row&7
#define SWZ(r, kb) ((r)*64 + ((kb) ^ (((r)&7)<<3)))
// attn swizzle: f(row) = (row&3) | ((row>>3)&1)<<2  (2-way for linear and permuted reads)
#define F2(r) ((((r)&3)) | ((((r)>>3)&1)<<2))
#define SWZ2(r, kb) ((r)*64 + ((kb) ^ (F2(r)<<3)))

#define WAITV(N) do{ asm volatile("s_waitcnt vmcnt(" #N ")" ::: "memory"); }while(0)
#define BAR() do{ __builtin_amdgcn_s_barrier(); __builtin_amdgcn_sched_barrier(0); }while(0)

template<int NC>
__device__ __forceinline__ void stage_swz(const short* __restrict__ g, int rowStride,
                                          short* shbase, int w, int l){
  #pragma unroll
  for(int i = 0; i < NC; ++i){
    int byte = (w*NC + i)*1024 + l*16;
    int row = byte >> 7;
    int gs = ((byte >> 4) & 7) ^ (row & 7);
    const short* src = g + (size_t)row*rowStride + gs*8;
    __builtin_amdgcn_global_load_lds((const __attribute__((address_space(1))) void*)src,
        (__attribute__((address_space(3))) void*)(shbase + (w*NC + i)*512), 16, 0, 0);
  }
}
template<int NC>
__device__ __forceinline__ void stage_swz2(const short* __restrict__ g, int rowStride,
                                           short* shbase, int w, int l){
  #pragma unroll
  for(int i = 0; i < NC; ++i){
    int byte = (w*NC + i)*1024 + l*16;
    int row = byte >> 7;
    int gs = ((byte >> 4) & 7) ^ F2(row);
    const short* src = g + (size_t)row*rowStride + gs*8;
    __builtin_amdgcn_global_load_lds((const __attribute__((address_space(1))) void*)src,
        (__attribute__((address_space(3))) void*)(shbase + (w*NC + i)*512), 16, 0, 0);
  }
}

// ---------------- fused pre-pass: weight transposes + qkv cast + mask bias ----------------
__global__ __launch_bounds__(256) void k_pre(const float* __restrict__ q,
        const float* __restrict__ k, const float* __restrict__ v,
        const int* __restrict__ mask,
        const float* __restrict__ w0, const float* __restrict__ w1,
        const float* __restrict__ w2, const float* __restrict__ w3,
        short* __restrict__ wT, short* __restrict__ qkvc, float* __restrict__ mb){
  __shared__ float tt[32][33];
  const int bi = blockIdx.x, t = threadIdx.x;
  if(bi < 1024){
    const int z = bi >> 8;
    const float* w = z == 0 ? w0 : z == 1 ? w1 : z == 2 ? w2 : w3;
    short* wt = wT + z * 262144;
    const int bxy = bi & 255;
    const int bx = (bxy & 15) * 32, by = (bxy >> 4) * 32;
    const int tx = t & 31, ty = t >> 5;
    #pragma unroll
    for(int i = 0; i < 32; i += 8) tt[ty + i][tx] = w[(by + ty + i) * D_ + bx + tx];
    __syncthreads();
    #pragma unroll
    for(int i = 0; i < 32; i += 8) wt[(bx + ty + i) * D_ + by + tx] = f2bf(tt[tx][ty + i]);
  } else if(bi < 7168){
    const int ci = bi - 1024;
    const int z = ci >> 11;
    const float* s = z == 0 ? q : z == 1 ? k : v;
    short* d = qkvc + (size_t)z * (B_ * S_ * D_);
    int i = (ci & 2047) * 256 + t;
    float4 a = ((const float4*)s)[i * 2];
    float4 b = ((const float4*)s)[i * 2 + 1];
    short8 o;
    o[0]=f2bf(a.x); o[1]=f2bf(a.y); o[2]=f2bf(a.z); o[3]=f2bf(a.w);
    o[4]=f2bf(b.x); o[5]=f2bf(b.y); o[6]=f2bf(b.z); o[7]=f2bf(b.w);
    ((short8*)d)[i] = o;
  } else {
    int i = (bi - 7168) * 256 + t;
    mb[i] = mask[i] ? -1.0e9f : 0.0f;
  }
}

// ---------------- fused QKV GEMM: 128x128 tile, 4 waves, m97 single-buffer ----------------
__global__ __launch_bounds__(256) void k_gemm_qkv(const short* __restrict__ Xall,
        const short* __restrict__ WTall, const float* __restrict__ b0,
        const float* __restrict__ b1, const float* __restrict__ b2,
        short* __restrict__ qh, short* __restrict__ kh, short* __restrict__ vvt){
  __shared__ __align__(16) short As[8192];
  __shared__ __align__(16) short Bs[8192];
  const int z = blockIdx.z;
  const short* X  = Xall + (size_t)z * (B_*S_*D_);
  const short* WT = WTall + (size_t)z * (D_*D_);
  const float* bias = z==0 ? b0 : (z==1 ? b1 : b2);
  const int t = threadIdx.x, l = t & 63, w = t >> 6;
  const int lr = l & 15, lg = l >> 4;
  const int m0 = blockIdx.x * 128, n0 = blockIdx.y * 128;
  const int wr = w >> 1, wc = w & 1;
  const short* Xb = X + (size_t)m0 * D_;
  const short* Wb = WT + (size_t)n0 * D_;
  f32x4 acc[4][4] = {};
  for(int kt = 0; kt < D_ / 64; ++kt){
    stage_swz<4>(Xb + kt*64, D_, As, w, l);
    stage_swz<4>(Wb + kt*64, D_, Bs, w, l);
    __syncthreads();
    #pragma unroll
    for(int ks = 0; ks < 2; ++ks){
      const int kb = ks*32 + lg*8;
      short8 a[4], b[4];
      #pragma unroll
      for(int mt = 0; mt < 4; ++mt)
        a[mt] = *reinterpret_cast<const short8*>(&As[SWZ(wr*64 + mt*16 + lr, kb)]);
      #pragma unroll
      for(int nt = 0; nt < 4; ++nt)
        b[nt] = *reinterpret_cast<const short8*>(&Bs[SWZ(wc*64 + nt*16 + lr, kb)]);
      __builtin_amdgcn_s_setprio(1);
      #pragma unroll
      for(int mt = 0; mt < 4; ++mt)
        #pragma unroll
        for(int nt = 0; nt < 4; ++nt)
          acc[mt][nt] = __builtin_amdgcn_mfma_f32_16x16x32_bf16(a[mt], b[nt], acc[mt][nt], 0, 0, 0);
      __builtin_amdgcn_s_setprio(0);
    }
    __syncthreads();
  }
  #pragma unroll
  for(int mt = 0; mt < 4; ++mt){
    #pragma unroll
    for(int nt = 0; nt < 4; ++nt){
      const int n = n0 + wc*64 + nt*16 + lr;
      const int m4 = m0 + wr*64 + mt*16 + lg*4;
      float vals[4];
      #pragma unroll
      for(int r = 0; r < 4; ++r) vals[r] = acc[mt][nt][r] + bias[n];
      if(z == 2){
        short4 pv4;
        pv4.x = f2bf(vals[0]); pv4.y = f2bf(vals[1]); pv4.z = f2bf(vals[2]); pv4.w = f2bf(vals[3]);
        *reinterpret_cast<short4*>(&vvt[
            (((size_t)((m4 >> 11) * H_ + (n >> 6))) * DP_ + (n & 63)) * S_ + (m4 & 2047)]) = pv4;
      } else {
        short* dst = z == 0 ? qh : kh;
        #pragma unroll
        for(int r = 0; r < 4; ++r){
          int m = m4 + r;
          dst[(((size_t)((m >> 11) * H_ + (n >> 6))) * S_ + (m & 2047)) * DP_ + (n & 63)] = f2bf(vals[r]);
        }
      }
    }
  }
}

// ---------------- out GEMM: ctx[8192,512]bf16 @ woT + bo -> f32 ----------------
__global__ __launch_bounds__(256) void k_gemm_out(const short* __restrict__ X,
        const short* __restrict__ WT, const float* __restrict__ bias,
        float* __restrict__ Out){
  __shared__ __align__(16) short As[8192];
  __shared__ __align__(16) short Bs[8192];
  const int t = threadIdx.x, l = t & 63, w = t >> 6;
  const int lr = l & 15, lg = l >> 4;
  const int m0 = blockIdx.x * 128, n0 = blockIdx.y * 128;
  const int wr = w >> 1, wc = w & 1;
  const short* Xb = X + (size_t)m0 * D_;
  const short* Wb = WT + (size_t)n0 * D_;
  f32x4 acc[4][4] = {};
  for(int kt = 0; kt < D_ / 64; ++kt){
    stage_swz<4>(Xb + kt*64, D_, As, w, l);
    stage_swz<4>(Wb + kt*64, D_, Bs, w, l);
    __syncthreads();
    #pragma unroll
    for(int ks = 0; ks < 2; ++ks){
      const int kb = ks*32 + lg*8;
      short8 a[4], b[4];
      #pragma unroll
      for(int mt = 0; mt < 4; ++mt)
        a[mt] = *reinterpret_cast<const short8*>(&As[SWZ(wr*64 + mt*16 + lr, kb)]);
      #pragma unroll
      for(int nt = 0; nt < 4; ++nt)
        b[nt] = *reinterpret_cast<const short8*>(&Bs[SWZ(wc*64 + nt*16 + lr, kb)]);
      __builtin_amdgcn_s_setprio(1);
      #pragma unroll
      for(int mt = 0; mt < 4; ++mt)
        #pragma unroll
        for(int nt = 0; nt < 4; ++nt)
          acc[mt][nt] = __builtin_amdgcn_mfma_f32_16x16x32_bf16(a[mt], b[nt], acc[mt][nt], 0, 0, 0);
      __builtin_amdgcn_s_setprio(0);
    }
    __syncthreads();
  }
  #pragma unroll
  for(int mt = 0; mt < 4; ++mt){
    #pragma unroll
    for(int nt = 0; nt < 4; ++nt){
      const int n = n0 + wc*64 + nt*16 + lr;
      const int m4 = m0 + wr*64 + mt*16 + lg*4;
      #pragma unroll
      for(int r = 0; r < 4; ++r)
        Out[(size_t)(m4 + r) * D_ + n] = acc[mt][nt][r] + bias[n];
    }
  }
}

// ---------------- fused attention ----------------
// 8 waves, q-tile 128. Permuted-QK in-register PV (R7). Deep counted-vmcnt pipeline:
//   pass A: K ring-of-4 (slots 0/4096/8192/12288), stage kt+3, WAITV(2)/1/0 tails
//   pass B: K ring-3 (0/4096/8192), V ring-3 (12288/16384/20480), stage kt+2,
//           WAITV: kt0->2, kt1->6, last->8, else 10 (stores pad the suffix)
// Q overlays V slots 1,2 [16384,24576) (consumed to regs before V staging begins).
// LDS shorts: staging [0,24576), mask f32 [24576,28672) => 56 KB, 2 blocks/CU
__global__ __launch_bounds__(512, 4) void k_attn(const short* __restrict__ qh,
                                                 const short* __restrict__ kh,
                                                 const short* __restrict__ vt,
                                                 const float* __restrict__ mb,
                                                 float* __restrict__ attn,
                                                 short* __restrict__ ctx){
  __shared__ __align__(16) short Sh[28672];
  const int t = threadIdx.x, l = t & 63, w = t >> 6;
  const int lr = l & 15, lg = l >> 4;
  // XCD-aware bijective swizzle: 512 wgs; XCD x gets 4 bh x 16 q-tiles
  int lin = blockIdx.y * 16 + blockIdx.x;
  int sw = (lin & 7) * 64 + (lin >> 3);
  const int bh = sw >> 4, b = bh >> 3, h = bh & 7;
  const int q0 = (sw & 15) * 128;
  const short* Qb = qh + (size_t)bh * S_ * DP_ + (size_t)q0 * DP_;
  const short* Kb = kh + (size_t)bh * S_ * DP_;
  const short* Vtb = vt + (size_t)bh * DP_ * S_;
  const float* Mbb = mb + b * S_;
  float* Mlds = (float*)(Sh + 24576);
  const float scale = 0.125f;

  // prologue: Q (16KB -> [16384)), mask (8KB), K0,K1,K2 -> A-ring slots 0,1,2
  stage_swz2<2>(Qb, DP_, Sh + 16384, w, l);
  __builtin_amdgcn_global_load_lds(
      (const __attribute__((address_space(1))) void*)(Mbb + w*256 + l*4),
      (__attribute__((address_space(3))) void*)(Mlds + w*256 + l*4), 16, 0, 0);
  stage_swz2<1>(Kb, DP_, Sh, w, l);
  stage_swz2<1>(Kb + 4096, DP_, Sh + 4096, w, l);
  stage_swz2<1>(Kb + 8192, DP_, Sh + 8192, w, l);
  WAITV(3); BAR();                                  // Q+mask landed; K0..K2 in flight
  short8 bq0, bq1;
  {
    int r = w * 16 + lr;
    bq0 = *reinterpret_cast<const short8*>(&Sh[16384 + SWZ2(r, lg * 8)]);
    bq1 = *reinterpret_cast<const short8*>(&Sh[16384 + SWZ2(r, 32 + lg * 8)]);
  }

  // ---------------- pass A: row sums (K ring-of-4, distance 3) ----------------
  float ps = 0.f;
  for(int kt = 0; kt < NT_; ++kt){
    if(kt <= NT_ - 3){ WAITV(2); } else if(kt == NT_ - 2){ WAITV(1); } else { WAITV(0); }
    BAR();
    if(kt + 3 < NT_)
      stage_swz2<1>(Kb + (size_t)(kt + 3) * 4096, DP_, Sh + ((kt + 3) & 3) * 4096, w, l);
    const short* Kc = Sh + (kt & 3) * 4096;
    const float* Ml = Mlds + kt * 64;
    #pragma unroll
    for(int st = 0; st < 4; ++st){
      const float4 mv = *(const float4*)&Ml[st * 16 + lg * 4];
      short8 ak0 = *reinterpret_cast<const short8*>(&Kc[SWZ2(st * 16 + lr, lg * 8)]);
      short8 ak1 = *reinterpret_cast<const short8*>(&Kc[SWZ2(st * 16 + lr, 32 + lg * 8)]);
      __builtin_amdgcn_s_setprio(1);
      f32x4 c = {};
      c = __builtin_amdgcn_mfma_f32_16x16x32_bf16(ak0, bq0, c, 0, 0, 0);
      c = __builtin_amdgcn_mfma_f32_16x16x32_bf16(ak1, bq1, c, 0, 0, 0);
      __builtin_amdgcn_s_setprio(0);
      ps += __expf(__builtin_fmaf(c[0], scale, mv.x));
      ps += __expf(__builtin_fmaf(c[1], scale, mv.y));
      ps += __expf(__builtin_fmaf(c[2], scale, mv.z));
      ps += __expf(__builtin_fmaf(c[3], scale, mv.w));
    }
  }
  // pass-B prologue: all pass-A reads done after this barrier, then restage
  BAR();
  stage_swz2<1>(Kb, DP_, Sh, w, l);
  stage_swz2<1>(Vtb, S_, Sh + 12288, w, l);
  stage_swz2<1>(Kb + 4096, DP_, Sh + 4096, w, l);
  stage_swz2<1>(Vtb + 64, S_, Sh + 16384, w, l);
  ps += __shfl_xor(ps, 16, 64);
  ps += __shfl_xor(ps, 32, 64);
  const float rinv = 1.f / ps;

  // ---------------- pass B: attn write + in-register PV (rings of 3, distance 2) ----------------
  f32x4 o[4] = {};
  const int grow = ((lr >> 2) << 3) + (lr & 3);    // permuted A-row base for this lane
  for(int kt = 0; kt < NT_; ++kt){
    if(kt == 0){ WAITV(2); }
    else if(kt == 1){ WAITV(6); }
    else if(kt == NT_ - 1){ WAITV(8); }
    else { WAITV(10); }
    BAR();
    if(kt + 2 < NT_){
      stage_swz2<1>(Kb + (size_t)(kt + 2) * 4096, DP_, Sh + ((kt + 2) % 3) * 4096, w, l);
      stage_swz2<1>(Vtb + (size_t)(kt + 2) * 64, S_, Sh + 12288 + ((kt + 2) % 3) * 4096, w, l);
    }
    const short* Kc = Sh + (kt % 3) * 4096;
    const short* Vc = Sh + 12288 + (kt % 3) * 4096;
    const float* Ml = Mlds + kt * 64;
    const int q = q0 + w * 16 + lr;
    i32x4 pav[2];
    #pragma unroll
    for(int st = 0; st < 4; ++st){
      const int ks = st >> 1, h4 = st & 1;
      const int row = grow + h4 * 4 + ks * 32;     // permuted A rows
      const int mcol = ks * 32 + h4 * 4 + lg * 8;  // k-columns this lane produces
      const float4 mv = *(const float4*)&Ml[mcol];
      short8 ak0 = *reinterpret_cast<const short8*>(&Kc[SWZ2(row, lg * 8)]);
      short8 ak1 = *reinterpret_cast<const short8*>(&Kc[SWZ2(row, 32 + lg * 8)]);
      __builtin_amdgcn_s_setprio(1);
      f32x4 c = {};
      c = __builtin_amdgcn_mfma_f32_16x16x32_bf16(ak0, bq0, c, 0, 0, 0);
      c = __builtin_amdgcn_mfma_f32_16x16x32_bf16(ak1, bq1, c, 0, 0, 0);
      __builtin_amdgcn_s_setprio(0);
      float4 pw;
      pw.x = __expf(__builtin_fmaf(c[0], scale, mv.x)) * rinv;
      pw.y = __expf(__builtin_fmaf(c[1], scale, mv.y)) * rinv;
      pw.z = __expf(__builtin_fmaf(c[2], scale, mv.z)) * rinv;
      pw.w = __expf(__builtin_fmaf(c[3], scale, mv.w)) * rinv;
      *reinterpret_cast<float4*>(&attn[((size_t)bh * S_ + q) * S_ + kt * 64 + mcol]) = pw;
      pav[ks][h4 * 2 + 0] = cvtpk(pw.x, pw.y);
      pav[ks][h4 * 2 + 1] = cvtpk(pw.z, pw.w);
    }
    #pragma unroll
    for(int ks = 0; ks < 2; ++ks){
      short8 pa = __builtin_bit_cast(short8, pav[ks]);
      __builtin_amdgcn_s_setprio(1);
      #pragma unroll
      for(int dt = 0; dt < 4; ++dt){
        short8 vb = *reinterpret_cast<const short8*>(&Vc[SWZ2(dt * 16 + lr, ks * 32 + lg * 8)]);
        o[dt] = __builtin_amdgcn_mfma_f32_16x16x32_bf16(pa, vb, o[dt], 0, 0, 0);
      }
      __builtin_amdgcn_s_setprio(0);
    }
  }
  // write context (head-merged bf16 [B][S][512]); o already normalized
  #pragma unroll
  for(int dt = 0; dt < 4; ++dt){
    #pragma unroll
    for(int r = 0; r < 4; ++r){
      int q = q0 + w * 16 + lg * 4 + r;
      int dd = h * 64 + dt * 16 + lr;
      ctx[((size_t)b * S_ + q) * D_ + dd] = f2bf(o[dt][r]);
    }
  }
}

extern "C" void kernel_launch(void* const* d_in, const int* in_sizes, int n_in,
                              void* d_out, int out_size, void* d_ws, size_t ws_size,
                              hipStream_t stream){
  const float* q  = (const float*)d_in[0];
  const float* k  = (const float*)d_in[1];
  const float* v  = (const float*)d_in[2];
  const int* mask = (const int*)d_in[3];
  const float* wq = (const float*)d_in[4];
  const float* bq = (const float*)d_in[5];
  const float* wk = (const float*)d_in[6];
  const float* bk = (const float*)d_in[7];
  const float* wv = (const float*)d_in[8];
  const float* bv = (const float*)d_in[9];
  const float* wo = (const float*)d_in[10];
  const float* bo = (const float*)d_in[11];

  float* out  = (float*)d_out;
  float* attn = out + (size_t)B_ * S_ * D_;

  char* ws = (char*)d_ws;
  short* qkvc = (short*)ws;                        // bf16 casts of q,k,v: 3 x 8 MiB
  short* qh  = (short*)(ws + 25165824);            // bf16 [B][H][S][64]
  short* kh  = (short*)(ws + 33554432);
  short* vvt = (short*)(ws + 41943040);            // bf16 [B][H][64][S]
  short* ctx = (short*)(ws + 50331648);            // bf16 [B][S][512]
  short* wT  = (short*)(ws + 58720256);            // bf16 [512][512] x4 transposed
  float* mb  = (float*)(ws + 58720256 + 4 * 524288);  // f32 [B][S] mask bias

  hipLaunchKernelGGL(k_pre, dim3(7200), dim3(256), 0, stream,
                     q, k, v, mask, wq, wk, wv, wo, wT, qkvc, mb);

  hipLaunchKernelGGL(k_gemm_qkv, dim3(64, 4, 3), dim3(256), 0, stream,
                     qkvc, wT, bq, bk, bv, qh, kh, vvt);

  hipLaunchKernelGGL(k_attn, dim3(16, 32), dim3(512), 0, stream, qh, kh, vvt, mb, attn, ctx);

  hipLaunchKernelGGL(k_gemm_out, dim3(64, 4), dim3(256), 0, stream, ctx, wT + 3 * 262144, bo, out);
}